// Round 11
// baseline (96.021 us; speedup 1.0000x reference)
//
#include <hip/hip_runtime.h>

typedef __attribute__((ext_vector_type(8))) short short8v;
typedef __attribute__((ext_vector_type(4))) float f32x4;
typedef __attribute__((ext_vector_type(16))) float f32x16;
typedef unsigned short u16;
typedef unsigned int u32;

#define MFMA __builtin_amdgcn_mfma_f32_16x16x32_bf16
#define MFMA32 __builtin_amdgcn_mfma_f32_32x32x16_bf16

// ---------- helpers ----------
__device__ __forceinline__ u16 f2b(float f) {
  u32 u = __float_as_uint(f);
  u = (u + 0x7FFFu + ((u >> 16) & 1u)) >> 16;
  return (u16)u;
}
__device__ __forceinline__ void g2l16(const void* g, void* l) {
  __builtin_amdgcn_global_load_lds(
      (const __attribute__((address_space(1))) unsigned int*)g,
      (__attribute__((address_space(3))) unsigned int*)l, 16, 0, 0);
}

// sizes
#define N_TOK 2048
#define DIM 1024
#define NH 16
#define HD 64

// Q pre-scale: hd^-0.5 * log2(e)  (softmax runs in exp2 domain)
#define QSCALE 0.18033688011112042f

// workspace layout (bytes)
#define OFF_PERM 0
#define OFF_CNT 8192
#define OFF_XPB 16384
#define OFF_WT (OFF_XPB + 4194304)          // 16 MB: [tensor][expert][1024][1024] bf16, WT[n][k]
#define OFF_Q (OFF_WT + 16777216)
#define OFF_K (OFF_Q + 4194304)
#define OFF_VT (OFF_K + 4194304)            // [16][64][2048] bf16
#define OFF_AT (OFF_VT + 4194304)
#define OFF_O (OFF_AT + 4194304)            // f32 [2048][1024]
#define OFF_O2 (OFF_O + 8388608)            // f32 [2048][1024] split-K partial

// ---------- fused: weight transpose-cast (z<8) + prep partition (z==8) ----------
__global__ __launch_bounds__(256) void wcast_prep(const float* __restrict__ wq,
                                                  const float* __restrict__ wk,
                                                  const float* __restrict__ wv,
                                                  const float* __restrict__ wo,
                                                  u16* __restrict__ wT,
                                                  const void* __restrict__ masks,
                                                  int* __restrict__ perm,
                                                  int* __restrict__ cnt) {
  __shared__ float t[32][33];
  __shared__ u32 red[256];
  __shared__ int scan[256];
  const int tx = threadIdx.x, ty = threadIdx.y;
  if (blockIdx.z == 8) {
    if (blockIdx.x != 0 || blockIdx.y != 0) return;
    const int tid = ty * 32 + tx;
    const u32* mw = (const u32*)masks;
    u32 mx = 0;
    for (int i = tid; i < 1024; i += 256) { u32 v = mw[i]; mx = mx > v ? mx : v; }
    red[tid] = mx;
    __syncthreads();
    for (int off = 128; off; off >>= 1) {
      if (tid < off) red[tid] = red[tid] > red[tid + off] ? red[tid] : red[tid + off];
      __syncthreads();
    }
    const bool isbyte = red[0] > 1u;
    int md[8];
    int c0loc = 0;
    #pragma unroll
    for (int j = 0; j < 8; ++j) {
      const int n = tid * 8 + j;
      int m1;
      if (isbyte) m1 = ((const unsigned char*)masks)[N_TOK + n] != 0;
      else        m1 = mw[N_TOK + n] != 0;
      md[j] = m1;
      c0loc += (m1 == 0);
    }
    scan[tid] = c0loc;
    __syncthreads();
    for (int off = 1; off < 256; off <<= 1) {
      int v = (tid >= off) ? scan[tid - off] : 0;
      __syncthreads();
      scan[tid] += v;
      __syncthreads();
    }
    const int incl = scan[tid];
    const int total0 = scan[255];
    const int excl0 = incl - c0loc;
    int p0 = excl0;
    int p1 = total0 + (tid * 8 - excl0);
    #pragma unroll
    for (int j = 0; j < 8; ++j) {
      const int n = tid * 8 + j;
      if (!md[j]) perm[p0++] = n; else perm[p1++] = n;
    }
    if (tid == 0) cnt[0] = total0;
    return;
  }
  const int mat = blockIdx.z;               // tensor*2 + expert
  const int tensor = mat >> 1, expert = mat & 1;
  const float* src = (tensor == 0) ? wq : (tensor == 1) ? wk : (tensor == 2) ? wv : wo;
  src += (size_t)expert * (1 << 20);
  u16* dst = wT + ((size_t)mat << 20);
  const int k0 = blockIdx.x * 32, n0 = blockIdx.y * 32;
  #pragma unroll
  for (int r = 0; r < 4; ++r)
    t[ty + 8 * r][tx] = src[(size_t)(k0 + ty + 8 * r) * DIM + n0 + tx];
  __syncthreads();
  // vectorized u32-pair stores: thread -> (row=n, 2 k-pairs)
  const int tid = ty * 32 + tx;
  const int row = tid >> 3, pr = tid & 7;
  u32* dst32 = (u32*)(dst + (size_t)(n0 + row) * DIM + k0);
  #pragma unroll
  for (int j = 0; j < 2; ++j) {
    const int kp = pr + j * 8;
    u32 val;
    asm("v_cvt_pk_bf16_f32 %0, %1, %2" : "=v"(val)
        : "v"(t[2 * kp][row]), "v"(t[2 * kp + 1][row]));
    dst32[kp] = val;
  }
}

// ---------- gather + cast x -> xp bf16 ----------
__global__ __launch_bounds__(256) void gather_cast(const float* __restrict__ x,
                                                   const int* __restrict__ perm,
                                                   u16* __restrict__ xpb) {
  const int i = blockIdx.x;
  const int src = perm[i];
  const int tid = threadIdx.x;
  float4 v = ((const float4*)(x + (size_t)src * DIM))[tid];
  ushort4 o;
  o.x = f2b(v.x); o.y = f2b(v.y); o.z = f2b(v.z); o.w = f2b(v.w);
  ((ushort4*)(xpb + (size_t)i * DIM))[tid] = o;
}

// ---------- QKV GEMM: BK=64, T2 swizzle; z==2 writes V^T via LDS transpose ----------
__global__ __launch_bounds__(256) void gemm_qkv(const u16* __restrict__ X,
                                                const u16* __restrict__ WTall,
                                                float qscale,
                                                u16* __restrict__ oq,
                                                u16* __restrict__ ok,
                                                u16* __restrict__ vT,
                                                const int* __restrict__ cntp) {
  const int z = blockIdx.z;                  // 0=q 1=k 2=v
  const int e = blockIdx.y >> 4;
  const int mt = blockIdx.y & 15;
  const int c0 = cntp[0];
  const int lo = e ? c0 : 0;
  const int hi = e ? N_TOK : c0;
  const int rb = mt * 128;
  if (rb >= hi || rb + 128 <= lo) return;
  const int cb = blockIdx.x * 128;
  const u16* W = WTall + ((size_t)(z * 2 + e) << 20);
  const float scl = (z == 0) ? qscale : 1.f;

  const int tid = threadIdx.x;
  const int w = tid >> 6, l = tid & 63, lg = l >> 4, ln = l & 15;
  const int wm = (w >> 1) * 64, wn = (w & 1) * 64;

  __shared__ __align__(16) char smem[65536];   // 2 bufs x (A 16K + B 16K)

  auto stage = [&](int it, int b_) {
    #pragma unroll
    for (int c = 0; c < 8; ++c) {
      const int j = tid + c * 256;             // 0..2047
      const int isB = j >> 10;
      const int cc = j & 1023;
      const int row = cc >> 3;
      const int colb = ((cc & 7) * 16) ^ ((row & 7) << 4);  // pre-swizzled source
      const char* base = isB ? (const char*)W + (size_t)(cb + row) * 2048
                             : (const char*)X + (size_t)(rb + row) * 2048;
      g2l16(base + it * 128 + colb, &smem[b_ * 32768 + isB * 16384 + cc * 16]);
    }
  };

  f32x4 acc[4][4];
  #pragma unroll
  for (int i = 0; i < 4; ++i)
    #pragma unroll
    for (int j = 0; j < 4; ++j) acc[i][j] = (f32x4){0.f, 0.f, 0.f, 0.f};

  const int aswz = (ln & 7) << 4;
  stage(0, 0);
  __syncthreads();
  for (int ii = 0; ii < 16; ++ii) {
    const int b_ = ii & 1;
    if (ii < 15) stage(ii + 1, b_ ^ 1);
    #pragma unroll
    for (int ks = 0; ks < 2; ++ks) {
      short8v a[4], bb[4];
      #pragma unroll
      for (int mi = 0; mi < 4; ++mi)
        a[mi] = *(const short8v*)&smem[b_ * 32768 + (wm + mi * 16 + ln) * 128 +
                                       ((ks * 64 + lg * 16) ^ aswz)];
      #pragma unroll
      for (int ni = 0; ni < 4; ++ni)
        bb[ni] = *(const short8v*)&smem[b_ * 32768 + 16384 + (wn + ni * 16 + ln) * 128 +
                                        ((ks * 64 + lg * 16) ^ aswz)];
      __builtin_amdgcn_s_setprio(1);
      #pragma unroll
      for (int mi = 0; mi < 4; ++mi)
        #pragma unroll
        for (int ni = 0; ni < 4; ++ni)
          acc[mi][ni] = MFMA(a[mi], bb[ni], acc[mi][ni], 0, 0, 0);
      __builtin_amdgcn_s_setprio(0);
    }
    __syncthreads();
  }

  if (z < 2) {
    u16* OUT = z ? ok : oq;
    #pragma unroll
    for (int mi = 0; mi < 4; ++mi) {
      #pragma unroll
      for (int r = 0; r < 4; ++r) {
        const int row = rb + wm + mi * 16 + lg * 4 + r;
        if (row >= lo && row < hi) {
          #pragma unroll
          for (int ni = 0; ni < 4; ++ni)
            OUT[(size_t)row * DIM + cb + wn + ni * 16 + ln] = f2b(acc[mi][ni][r] * scl);
        }
      }
    }
  } else {
    // V^T epilogue: transpose acc [token][dim] -> vT[dim][token] via LDS.
    #pragma unroll
    for (int mi = 0; mi < 4; ++mi)
      #pragma unroll
      for (int ni = 0; ni < 4; ++ni) {
        const int dim = wn + ni * 16 + ln;
        const int tok = wm + mi * 16 + lg * 4;
        u32 p01, p23;
        asm("v_cvt_pk_bf16_f32 %0, %1, %2" : "=v"(p01) : "v"(acc[mi][ni][0]), "v"(acc[mi][ni][1]));
        asm("v_cvt_pk_bf16_f32 %0, %1, %2" : "=v"(p23) : "v"(acc[mi][ni][2]), "v"(acc[mi][ni][3]));
        *(uint2*)&smem[dim * 264 + tok * 2] = make_uint2(p01, p23);
      }
    __syncthreads();
    #pragma unroll 4
    for (int rr = 0; rr < 32; ++rr) {
      const int dim = w * 32 + rr;
      const u32 val = *(const u32*)&smem[dim * 264 + l * 4];
      const int tok = rb + 2 * l;
      u16* dst = vT + (size_t)(cb + dim) * 2048 + tok;
      if (tok >= lo && tok + 2 <= hi) {
        *(u32*)dst = val;
      } else {
        if (tok >= lo && tok < hi) dst[0] = (u16)(val & 0xFFFFu);
        if (tok + 1 >= lo && tok + 1 < hi) dst[1] = (u16)(val >> 16);
      }
    }
  }
}

// ---------- out-proj GEMM: 128x64 tile, BK=64, split-K2, f32 partials ----------
__global__ __launch_bounds__(256) void gemm_out(const u16* __restrict__ X,
                                                const u16* __restrict__ WTall,
                                                float* __restrict__ o0,
                                                float* __restrict__ o1,
                                                const int* __restrict__ cntp) {
  const int z = blockIdx.z;                  // K-half
  const int e = blockIdx.y >> 4;
  const int mt = blockIdx.y & 15;
  const int c0 = cntp[0];
  const int lo = e ? c0 : 0;
  const int hi = e ? N_TOK : c0;
  const int rb = mt * 128;
  if (rb >= hi || rb + 128 <= lo) return;
  const int cb = blockIdx.x * 64;
  float* OUT = z ? o1 : o0;
  const u16* W = WTall + ((size_t)(6 + e) << 20);
  const int kstart = z * 8;

  const int tid = threadIdx.x;
  const int w = tid >> 6, l = tid & 63, lg = l >> 4, ln = l & 15;
  const int wm = w * 32;

  __shared__ __align__(16) char smem[49152];   // 2 bufs x (A 16K + B 8K)

  auto stage = [&](int it, int b_) {
    #pragma unroll
    for (int c = 0; c < 6; ++c) {
      const int j = tid + c * 256;             // 0..1535
      const int isB = j >= 1024;
      const int cc = isB ? (j - 1024) : j;
      const int row = cc >> 3;
      const int colb = ((cc & 7) * 16) ^ ((row & 7) << 4);
      const char* base = isB ? (const char*)W + (size_t)(cb + row) * 2048
                             : (const char*)X + (size_t)(rb + row) * 2048;
      g2l16(base + it * 128 + colb, &smem[b_ * 24576 + isB * 16384 + cc * 16]);
    }
  };

  f32x4 acc[2][4];
  #pragma unroll
  for (int i = 0; i < 2; ++i)
    #pragma unroll
    for (int j = 0; j < 4; ++j) acc[i][j] = (f32x4){0.f, 0.f, 0.f, 0.f};

  const int aswz = (ln & 7) << 4;
  stage(kstart, 0);
  __syncthreads();
  for (int ii = 0; ii < 8; ++ii) {
    const int b_ = ii & 1;
    if (ii < 7) stage(kstart + ii + 1, b_ ^ 1);
    #pragma unroll
    for (int ks = 0; ks < 2; ++ks) {
      short8v a[2], bb[4];
      #pragma unroll
      for (int mi = 0; mi < 2; ++mi)
        a[mi] = *(const short8v*)&smem[b_ * 24576 + (wm + mi * 16 + ln) * 128 +
                                       ((ks * 64 + lg * 16) ^ aswz)];
      #pragma unroll
      for (int ni = 0; ni < 4; ++ni)
        bb[ni] = *(const short8v*)&smem[b_ * 24576 + 16384 + (ni * 16 + ln) * 128 +
                                        ((ks * 64 + lg * 16) ^ aswz)];
      __builtin_amdgcn_s_setprio(1);
      #pragma unroll
      for (int mi = 0; mi < 2; ++mi)
        #pragma unroll
        for (int ni = 0; ni < 4; ++ni)
          acc[mi][ni] = MFMA(a[mi], bb[ni], acc[mi][ni], 0, 0, 0);
      __builtin_amdgcn_s_setprio(0);
    }
    __syncthreads();
  }

  #pragma unroll
  for (int mi = 0; mi < 2; ++mi) {
    #pragma unroll
    for (int r = 0; r < 4; ++r) {
      const int row = rb + wm + mi * 16 + lg * 4 + r;
      if (row >= lo && row < hi) {
        #pragma unroll
        for (int ni = 0; ni < 4; ++ni)
          OUT[(size_t)row * DIM + cb + ni * 16 + ln] = acc[mi][ni][r];
      }
    }
  }
}

// ---------- flash attention: 8 waves x (1 qgroup, 1 key-quarter), barrier-free,
// wave-private single-buffered 8KB slices, reg-staged with early ds_writes.
// grid 512 blocks (32 qtiles x 16 heads, XCD-swizzled); 4 waves/SIMD target. ----------
__global__ __launch_bounds__(512, 4) void attn_fwd(const u16* __restrict__ qg,
                                                   const u16* __restrict__ kg,
                                                   const u16* __restrict__ vTg,
                                                   u16* __restrict__ og) {
  const int bid = blockIdx.x;
  const int wg = (bid & 7) * 64 + (bid >> 3);   // bijective XCD swizzle (512 = 8*64)
  const int qt = wg & 31, h = wg >> 5;
  const int tid = threadIdx.x, w = tid >> 6, l = tid & 63;
  const int g = w & 1, kq = w >> 1;             // qgroup (32 rows), key-quarter (512 keys)
  const int q31 = l & 31, hi = l >> 5;
  const int hi16 = hi * 16, hi4 = hi * 4;

  __shared__ __align__(16) char smem[67584];    // 8 waves x 8KB + 2KB merge m/l
  const int Kb = w * 8192, Vb = Kb + 4096;      // wave-private slice (single-buffered)

  // per-lane staging source bases (inverse-swizzled so LDS writes are linear)
  const int lr3 = l >> 3, lc3 = l & 7;
  const char* baseK = (const char*)kg + (size_t)(kq * 512 + lr3) * 2048 + h * 128 +
                      ((lc3 << 4) ^ (lr3 << 4));
  const int cpr = lc3 ^ lr3;                    // swizzled col/16 for V
  const int dhalf = (cpr >> 2) & 1;
  const char* baseV = (const char*)vTg + (size_t)(h * 64 + lr3 + dhalf * 32) * 4096 +
                      kq * 1024 + ((cpr & 3) << 4);

  // Q fragments (B-operand), one set of 32 q-cols for this wave's qgroup
  const char* qb0 = (const char*)qg + (size_t)(qt * 64 + g * 32 + q31) * 2048 + h * 128;
  short8v qf[4];
  #pragma unroll
  for (int t = 0; t < 4; ++t) qf[t] = *(const short8v*)(qb0 + t * 32 + hi16);

  uint4 rk0, rk1, rk2, rk3, rv0, rv1, rv2, rv3;
  auto loadKV = [&](int it) {
    const char* pk = baseK + (size_t)it * 65536;   // 32 key-rows x 2048B
    rk0 = *(const uint4*)(pk);
    rk1 = *(const uint4*)(pk + 16384);
    rk2 = *(const uint4*)(pk + 32768);
    rk3 = *(const uint4*)(pk + 49152);
    const char* pv = baseV + it * 64;              // 32 keys x 2B
    rv0 = *(const uint4*)(pv);
    rv1 = *(const uint4*)(pv + 32768);
    rv2 = *(const uint4*)(pv + 65536);
    rv3 = *(const uint4*)(pv + 98304);
  };
  auto writeK = [&]() {
    *(uint4*)&smem[Kb + 0 + l * 16] = rk0;
    *(uint4*)&smem[Kb + 1024 + l * 16] = rk1;
    *(uint4*)&smem[Kb + 2048 + l * 16] = rk2;
    *(uint4*)&smem[Kb + 3072 + l * 16] = rk3;
  };
  auto writeV = [&]() {
    *(uint4*)&smem[Vb + 0 + l * 16] = rv0;
    *(uint4*)&smem[Vb + 1024 + l * 16] = rv1;
    *(uint4*)&smem[Vb + 2048 + l * 16] = rv2;
    *(uint4*)&smem[Vb + 3072 + l * 16] = rv3;
  };

  float m_s = -1e30f, l_s = 0.f;
  f32x16 acc0, acc1;
  #pragma unroll
  for (int r = 0; r < 16; ++r) { acc0[r] = 0.f; acc1[r] = 0.f; }

  const int kswz = (q31 & 7) << 4;
  loadKV(0);
  writeK();
  writeV();
  loadKV(1);

  #pragma unroll 1
  for (int it = 0; it < 16; ++it) {
    // K frags (lane = key row q31); single buffer, program-order read->write
    short8v kf0 = *(const short8v*)&smem[Kb + q31 * 128 + ((0 + hi16) ^ kswz)];
    short8v kf1 = *(const short8v*)&smem[Kb + q31 * 128 + ((32 + hi16) ^ kswz)];
    short8v kf2 = *(const short8v*)&smem[Kb + q31 * 128 + ((64 + hi16) ^ kswz)];
    short8v kf3 = *(const short8v*)&smem[Kb + q31 * 128 + ((96 + hi16) ^ kswz)];
    if (it < 15) writeK();                     // regs hold it+1 K (loaded last iter)
    f32x16 s_;
    #pragma unroll
    for (int r = 0; r < 16; ++r) s_[r] = 0.f;
    __builtin_amdgcn_s_setprio(1);
    s_ = MFMA32(kf0, qf[0], s_, 0, 0, 0);
    s_ = MFMA32(kf1, qf[1], s_, 0, 0, 0);
    s_ = MFMA32(kf2, qf[2], s_, 0, 0, 0);
    s_ = MFMA32(kf3, qf[3], s_, 0, 0, 0);
    __builtin_amdgcn_s_setprio(0);

    // softmax (one q-set): in-lane tree + partner-half reduce
    float t0 = fmaxf(fmaxf(s_[0], s_[1]), fmaxf(s_[2], s_[3]));
    float t1 = fmaxf(fmaxf(s_[4], s_[5]), fmaxf(s_[6], s_[7]));
    float t2 = fmaxf(fmaxf(s_[8], s_[9]), fmaxf(s_[10], s_[11]));
    float t3 = fmaxf(fmaxf(s_[12], s_[13]), fmaxf(s_[14], s_[15]));
    float tmax = fmaxf(fmaxf(t0, t1), fmaxf(t2, t3));
    tmax = fmaxf(tmax, __shfl_xor(tmax, 32, 64));
    if (!__all(tmax <= m_s + 11.0f)) {         // defer-max (T13)
      const float mn = fmaxf(m_s, tmax);
      const float al = __builtin_amdgcn_exp2f(m_s - mn);
      m_s = mn;
      l_s *= al;
      #pragma unroll
      for (int r = 0; r < 16; ++r) {
        const float ar = __shfl(al, (r & 3) + 8 * (r >> 2) + hi4, 64);
        acc0[r] *= ar;
        acc1[r] *= ar;
      }
    }
    float p[16];
    #pragma unroll
    for (int r = 0; r < 16; ++r) p[r] = __builtin_amdgcn_exp2f(s_[r] - m_s);
    float rs = ((p[0] + p[1]) + (p[2] + p[3])) + ((p[4] + p[5]) + (p[6] + p[7])) +
               (((p[8] + p[9]) + (p[10] + p[11])) + ((p[12] + p[13]) + (p[14] + p[15])));
    rs += __shfl_xor(rs, 32, 64);
    l_s += rs;

    u32 c0, c1, c2, c3, c4, c5, c6, c7;
    asm("v_cvt_pk_bf16_f32 %0, %1, %2" : "=v"(c0) : "v"(p[0]), "v"(p[1]));
    asm("v_cvt_pk_bf16_f32 %0, %1, %2" : "=v"(c1) : "v"(p[2]), "v"(p[3]));
    asm("v_cvt_pk_bf16_f32 %0, %1, %2" : "=v"(c2) : "v"(p[4]), "v"(p[5]));
    asm("v_cvt_pk_bf16_f32 %0, %1, %2" : "=v"(c3) : "v"(p[6]), "v"(p[7]));
    asm("v_cvt_pk_bf16_f32 %0, %1, %2" : "=v"(c4) : "v"(p[8]), "v"(p[9]));
    asm("v_cvt_pk_bf16_f32 %0, %1, %2" : "=v"(c5) : "v"(p[10]), "v"(p[11]));
    asm("v_cvt_pk_bf16_f32 %0, %1, %2" : "=v"(c6) : "v"(p[12]), "v"(p[13]));
    asm("v_cvt_pk_bf16_f32 %0, %1, %2" : "=v"(c7) : "v"(p[14]), "v"(p[15]));
    asm volatile("v_permlane32_swap_b32 %0, %1" : "+v"(c0), "+v"(c2));
    asm volatile("v_permlane32_swap_b32 %0, %1" : "+v"(c1), "+v"(c3));
    asm volatile("v_permlane32_swap_b32 %0, %1" : "+v"(c4), "+v"(c6));
    asm volatile("v_permlane32_swap_b32 %0, %1" : "+v"(c5), "+v"(c7));
    union { u32 u[4]; short8v s; } pa0, pa1;
    pa0.u[0] = c0; pa0.u[1] = c1; pa0.u[2] = c2; pa0.u[3] = c3;
    pa1.u[0] = c4; pa1.u[1] = c5; pa1.u[2] = c6; pa1.u[3] = c7;

    // V frags then early writeV (program order), then PV
    short8v vf00 = *(const short8v*)&smem[Vb + q31 * 128 + ((0 + hi16) ^ kswz)];
    short8v vf01 = *(const short8v*)&smem[Vb + q31 * 128 + ((64 + hi16) ^ kswz)];
    short8v vf10 = *(const short8v*)&smem[Vb + q31 * 128 + ((32 + hi16) ^ kswz)];
    short8v vf11 = *(const short8v*)&smem[Vb + q31 * 128 + ((96 + hi16) ^ kswz)];
    if (it < 15) writeV();
    __builtin_amdgcn_s_setprio(1);
    acc0 = MFMA32(pa0.s, vf00, acc0, 0, 0, 0);
    acc1 = MFMA32(pa0.s, vf01, acc1, 0, 0, 0);
    acc0 = MFMA32(pa1.s, vf10, acc0, 0, 0, 0);
    acc1 = MFMA32(pa1.s, vf11, acc1, 0, 0, 0);
    __builtin_amdgcn_s_setprio(0);
    if (it < 14) loadKV(it + 2);
  }
  __syncthreads();

  // ---- per-qgroup 4-way split-K merge (staging LDS dead; reuse) ----
  float* mm = (float*)&smem[65536];             // m[g][kq][32], l at +256 floats
  if (l < 32) {
    mm[(g * 4 + kq) * 32 + l] = m_s;
    mm[256 + (g * 4 + kq) * 32 + l] = l_s;
  }
  __syncthreads();
  float M = mm[(g * 4 + 0) * 32 + q31];
  M = fmaxf(M, mm[(g * 4 + 1) * 32 + q31]);
  M = fmaxf(M, mm[(g * 4 + 2) * 32 + q31]);
  M = fmaxf(M, mm[(g * 4 + 3) * 32 + q31]);
  float L = 0.f;
  #pragma unroll
  for (int j = 0; j < 4; ++j)
    L += mm[256 + (g * 4 + j) * 32 + q31] *
         __builtin_amdgcn_exp2f(mm[(g * 4 + j) * 32 + q31] - M);
  const float aown = __builtin_amdgcn_exp2f(m_s - M);
  const float linv = 1.f / L;

  float* obuf = (float*)&smem[g * 8192];        // [32 q][64 d] f32 per qgroup
  #pragma unroll
  for (int round = 3; round >= 0; --round) {
    if (kq == round) {
      #pragma unroll
      for (int r = 0; r < 16; ++r) {
        const int qr = (r & 3) + 8 * (r >> 2) + hi4;
        const float ar = __shfl(aown, qr, 64);
        float* p0 = &obuf[qr * 64 + q31];
        float* p1 = &obuf[qr * 64 + 32 + q31];
        if (round == 3) {
          *p0 = acc0[r] * ar;
          *p1 = acc1[r] * ar;
        } else if (round > 0) {
          *p0 += acc0[r] * ar;
          *p1 += acc1[r] * ar;
        } else {
          const float li = __shfl(linv, qr, 64);
          const int row = qt * 64 + g * 32 + qr;
          og[(size_t)row * DIM + h * HD + q31] = f2b((acc0[r] * ar + *p0) * li);
          og[(size_t)row * DIM + h * HD + 32 + q31] = f2b((acc1[r] * ar + *p1) * li);
        }
      }
    }
    __syncthreads();
  }
}

// ---------- LayerNorm + per-modality affine + scatter (sums split-K partials) ----------
__global__ __launch_bounds__(256) void ln_scatter(const float* __restrict__ oa,
                                                  const float* __restrict__ ob,
                                                  const float* __restrict__ lnw,
                                                  const float* __restrict__ lnb,
                                                  const int* __restrict__ perm,
                                                  const int* __restrict__ cntp,
                                                  float* __restrict__ out) {
  const int i = blockIdx.x;
  const int tid = threadIdx.x, w = tid >> 6, l = tid & 63;
  const int mod = (i < cntp[0]) ? 0 : 1;
  float4 va = ((const float4*)(oa + (size_t)i * DIM))[tid];
  float4 vb = ((const float4*)(ob + (size_t)i * DIM))[tid];
  float4 v;
  v.x = va.x + vb.x; v.y = va.y + vb.y; v.z = va.z + vb.z; v.w = va.w + vb.w;
  float s = v.x + v.y + v.z + v.w;
  float ss = v.x * v.x + v.y * v.y + v.z * v.z + v.w * v.w;
  #pragma unroll
  for (int off = 1; off < 64; off <<= 1) {
    s += __shfl_xor(s, off, 64);
    ss += __shfl_xor(ss, off, 64);
  }
  __shared__ float rs4[4], rss4[4];
  if (l == 0) { rs4[w] = s; rss4[w] = ss; }
  __syncthreads();
  const float st = rs4[0] + rs4[1] + rs4[2] + rs4[3];
  const float sst = rss4[0] + rss4[1] + rss4[2] + rss4[3];
  const float mu = st * (1.f / DIM);
  const float var = sst * (1.f / DIM) - mu * mu;
  const float rstd = rsqrtf(var + 1e-5f);
  const int drow = perm[i];
  float4 g = ((const float4*)(lnw + (size_t)mod * DIM))[tid];
  float4 b = ((const float4*)(lnb + (size_t)mod * DIM))[tid];
  float4 rr;
  rr.x = (v.x - mu) * rstd * g.x + b.x;
  rr.y = (v.y - mu) * rstd * g.y + b.y;
  rr.z = (v.z - mu) * rstd * g.z + b.z;
  rr.w = (v.w - mu) * rstd * g.w + b.w;
  ((float4*)(out + (size_t)drow * DIM))[tid] = rr;
}

// ---------- launch ----------
extern "C" void kernel_launch(void* const* d_in, const int* in_sizes, int n_in,
                              void* d_out, int out_size, void* d_ws, size_t ws_size,
                              hipStream_t stream) {
  const float* x = (const float*)d_in[0];
  const void* masks = d_in[1];
  const float* wq = (const float*)d_in[3];
  const float* wk = (const float*)d_in[4];
  const float* wv = (const float*)d_in[5];
  const float* wo = (const float*)d_in[6];
  const float* lnw = (const float*)d_in[7];
  const float* lnb = (const float*)d_in[8];

  char* ws = (char*)d_ws;
  int* perm = (int*)(ws + OFF_PERM);
  int* cnt = (int*)(ws + OFF_CNT);
  u16* xpb = (u16*)(ws + OFF_XPB);
  u16* wT = (u16*)(ws + OFF_WT);
  u16* q = (u16*)(ws + OFF_Q);
  u16* k = (u16*)(ws + OFF_K);
  u16* vT = (u16*)(ws + OFF_VT);
  u16* at = (u16*)(ws + OFF_AT);
  float* o = (float*)(ws + OFF_O);
  float* o2 = (float*)(ws + OFF_O2);
  float* out = (float*)d_out;

  wcast_prep<<<dim3(32, 32, 9), dim3(32, 8), 0, stream>>>(wq, wk, wv, wo, wT, masks, perm, cnt);
  gather_cast<<<N_TOK, 256, 0, stream>>>(x, perm, xpb);
  gemm_qkv<<<dim3(8, 32, 3), 256, 0, stream>>>(xpb, wT, QSCALE, q, k, vT, cnt);
  attn_fwd<<<512, 512, 0, stream>>>(q, k, vT, at);
  gemm_out<<<dim3(16, 32, 2), 256, 0, stream>>>(at, wT, o, o2, cnt);
  ln_scatter<<<N_TOK, 256, 0, stream>>>(o, o2, lnw, lnb, perm, cnt, out);
}